// Round 5
// baseline (214.159 us; speedup 1.0000x reference)
//
#include <hip/hip_runtime.h>
#include <hip/hip_bf16.h>
#include <cstdint>
#include <cstddef>

// B=8192, CIN=16, 6x6->5x5 (k=2 VALID), FM=64, DK=DV=NH=32 (dkh=1), HID=128, OUT=5.
// k1 (fused): conv+qkv implicit GEMM -> LDS -> attention -> 1x1-conv MFMA,
//             plus distributed w1 permute/cast for k2 (stream-ordered visibility).
// act layout [b][pos][ch] (dense K-permuted); w1bp pre-permuted to match.

typedef __attribute__((ext_vector_type(4))) float f32x4;
typedef __attribute__((ext_vector_type(8))) __bf16 bf16x8;
typedef __attribute__((ext_vector_type(4))) __bf16 bf16x4;

#define LOG2E 1.4426950408889634f

// v_mfma_f32_16x16x32_bf16 (bench-verified layout R2-R4):
// A: lane holds A[m=lane&15][k=quad*8+j]; B: W[n=lane&15][k=quad*8+j];
// C/D: col=lane&15, row=quad*4+reg.
__device__ __forceinline__ f32x4 mfma16(bf16x8 a, bf16x8 b, f32x4 c) {
  return __builtin_amdgcn_mfma_f32_16x16x32_bf16(a, b, c, 0, 0, 0);
}

// ---------------- k1: fused conv+qkv GEMM + attention + 1x1 conv (+ weight prep) ----------------
// 2048 blocks x 256 thr (4 waves); block = 4 batches -> GEMM M=100 (7 m-tiles).
// LDS: region A (6400 B) = xs (phase1: x bf16, 4*576) / as_ (phase2/3: [row][head], 100*32)
//      region B (21504 B) = qs [bl][ch 0..95][pos pad 28] (56 B rows, conflict-free;
//                           k channels pre-scaled by log2e for exp2 softmax)
__global__ __launch_bounds__(256) void k1(
    const float* __restrict__ x,
    const float* __restrict__ conv_w, const float* __restrict__ conv_b,
    const float* __restrict__ qkv_w,  const float* __restrict__ qkv_b,
    const float* __restrict__ attn_w, const float* __restrict__ attn_b,
    const float* __restrict__ w1, const float* __restrict__ w2,
    __hip_bfloat16* __restrict__ act,
    __hip_bfloat16* __restrict__ w1bp, __hip_bfloat16* __restrict__ w2b) {
  const int t = threadIdx.x;
  const int lane = t & 63, wave = t >> 6;
  const int l15 = lane & 15, quad = lane >> 4;
  const int b0 = blockIdx.x * 4;

  __shared__ __align__(16) char lds_raw[6400 + 21504];
  __bf16* xs  = (__bf16*)lds_raw;          // phase 1 (2304 elems)
  __bf16* as_ = (__bf16*)lds_raw;          // phase 2/3 (3200 elems, stride 32 = 16B-aligned rows)
  __bf16* qs  = (__bf16*)(lds_raw + 6400); // q:0-31 k:32-63(x log2e) v:64-95, stride 28

  // ---- distributed prep for k2 (no ordering needed vs this kernel's phases) ----
  {
    int i = blockIdx.x * 100 + t;
    if (t < 100) {  // 2048*100 = 204800 = 128*1600 exactly
      int n = i / 1600, r = i - n * 1600;
      int c = r & 63, p = r >> 6;
      w1bp[i] = __float2bfloat16(w1[n * 1600 + c * 25 + p]);
    }
    if (blockIdx.x < 32) w2b[blockIdx.x * 256 + t] = __float2bfloat16(w2[blockIdx.x * 256 + t]);
  }

  // ---- stage x -> bf16 LDS (2304 floats, coalesced) ----
  const float* xb = x + (size_t)b0 * 576;
#pragma unroll
  for (int i = 0; i < 9; ++i) {
    int f = t + i * 256;
    xs[f] = __float2bfloat16(xb[f]);
  }

  // ---- B-frags direct from global fp32 (replaces wqb prep kernel) + biases ----
  bf16x8 bfr[8][2];
  float bias[8];
#pragma unroll
  for (int nt = 0; nt < 8; ++nt) {
    int ch = nt * 16 + l15;
    const float* wrow = (ch < 32) ? (conv_w + ch * 64) : (qkv_w + (ch - 32) * 64);
    bias[nt] = (ch < 32) ? conv_b[ch] : qkv_b[ch - 32];
#pragma unroll
    for (int ks = 0; ks < 2; ++ks) {
      float4 a = *(const float4*)(wrow + ks * 32 + quad * 8);
      float4 b = *(const float4*)(wrow + ks * 32 + quad * 8 + 4);
      bf16x8 f;
      f[0] = (__bf16)__float2bfloat16(a.x); f[1] = (__bf16)__float2bfloat16(a.y);
      f[2] = (__bf16)__float2bfloat16(a.z); f[3] = (__bf16)__float2bfloat16(a.w);
      f[4] = (__bf16)__float2bfloat16(b.x); f[5] = (__bf16)__float2bfloat16(b.y);
      f[6] = (__bf16)__float2bfloat16(b.z); f[7] = (__bf16)__float2bfloat16(b.w);
      bfr[nt][ks] = f;
    }
  }
  __syncthreads();

  // ---- phase 1: implicit GEMM, M=100, N=128, K=64 ----
  for (int mt = wave; mt < 7; mt += 4) {
    int row = mt * 16 + l15;
    int rc = row < 99 ? row : 99;
    int bl = rc / 25, pos = rc - bl * 25;
    int ii = pos / 5, jj = pos - ii * 5;
    const __bf16* xp = xs + bl * 576 + ii * 6 + jj;
    bf16x8 af[2];
#pragma unroll
    for (int ks = 0; ks < 2; ++ks) {
      const __bf16* p0 = xp + (ks * 8 + quad * 2) * 36;
      bf16x8 a;
      a[0] = p0[0];  a[1] = p0[1];  a[2] = p0[6];  a[3] = p0[7];
      a[4] = p0[36]; a[5] = p0[37]; a[6] = p0[42]; a[7] = p0[43];
      af[ks] = a;
    }
    f32x4 acc[8];
#pragma unroll
    for (int nt = 0; nt < 8; ++nt) acc[nt] = (f32x4){0.f, 0.f, 0.f, 0.f};
#pragma unroll
    for (int ks = 0; ks < 2; ++ks)
#pragma unroll
      for (int nt = 0; nt < 8; ++nt)
        acc[nt] = mfma16(af[ks], bfr[nt][ks], acc[nt]);

#pragma unroll
    for (int r = 0; r < 4; ++r) {
      int orow = mt * 16 + quad * 4 + r;
      if (orow < 100) {
        int ob = orow / 25, op = orow - ob * 25;
#pragma unroll
        for (int nt = 0; nt < 8; ++nt) {
          float v = acc[nt][r] + bias[nt];
          if (nt < 2) {  // conv_out ch 0..31 -> global with relu
            act[((size_t)(b0 + ob) * 25 + op) * 64 + nt * 16 + l15] =
                __float2bfloat16(fmaxf(v, 0.f));
          } else {       // qkv ch 0..95 -> LDS; k-channels (nt 4,5) pre-scaled by log2e
            if (nt == 4 || nt == 5) v *= LOG2E;
            qs[(ob * 96 + (nt - 2) * 16 + l15) * 28 + op] = __float2bfloat16(v);
          }
        }
      }
    }
  }
  __syncthreads();

  // ---- phase 2: attention, dkh=1; softmax without max-sub (|q.k| << fp32 exp range),
  //      e = exp2(q * k*log2e). 2 threads/head split i into 0..12 / 12..24 (i=12 dup, benign).
  {
    const int pair = t & 127, half = t >> 7;
    const int bl = pair >> 5, n = pair & 31;
    const __bf16* qp = qs + (bl * 96 + n) * 28;
    const __bf16* kp = qp + 32 * 28;
    const __bf16* vp = qp + 64 * 28;
    float kl[25], vv[25];
#pragma unroll
    for (int c4 = 0; c4 < 6; ++c4) {
      bf16x4 b = *(const bf16x4*)(kp + c4 * 4);
      bf16x4 c = *(const bf16x4*)(vp + c4 * 4);
#pragma unroll
      for (int z = 0; z < 4; ++z) {
        kl[c4 * 4 + z] = (float)b[z];
        vv[c4 * 4 + z] = (float)c[z];
      }
    }
    kl[24] = (float)kp[24]; vv[24] = (float)vp[24];

    const int i0 = half * 12;
    float qv[13];
#pragma unroll
    for (int z = 0; z < 13; ++z) qv[z] = (float)qp[i0 + z];

#pragma unroll
    for (int z = 0; z < 13; ++z) {
      const float qi = qv[z];
      float s0 = 0.f, s1 = 0.f, s2 = 0.f, s3 = 0.f, s4 = 0.f;
      float o0 = 0.f, o1 = 0.f, o2 = 0.f, o3 = 0.f, o4 = 0.f;
#pragma unroll
      for (int g = 0; g < 5; ++g) {
        float e0 = exp2f(qi * kl[g * 5 + 0]);
        float e1 = exp2f(qi * kl[g * 5 + 1]);
        float e2 = exp2f(qi * kl[g * 5 + 2]);
        float e3 = exp2f(qi * kl[g * 5 + 3]);
        float e4 = exp2f(qi * kl[g * 5 + 4]);
        s0 += e0; o0 = __builtin_fmaf(e0, vv[g * 5 + 0], o0);
        s1 += e1; o1 = __builtin_fmaf(e1, vv[g * 5 + 1], o1);
        s2 += e2; o2 = __builtin_fmaf(e2, vv[g * 5 + 2], o2);
        s3 += e3; o3 = __builtin_fmaf(e3, vv[g * 5 + 3], o3);
        s4 += e4; o4 = __builtin_fmaf(e4, vv[g * 5 + 4], o4);
      }
      float ss = ((s0 + s1) + (s2 + s3)) + s4;
      float oo = ((o0 + o1) + (o2 + o3)) + o4;
      as_[(bl * 25 + i0 + z) * 32 + n] = __float2bfloat16(oo * __builtin_amdgcn_rcpf(ss));
    }
  }
  __syncthreads();

  // ---- phase 3: 1x1 conv via MFMA. M=100 rows, K=32 heads, N=32 ----
  {
    bf16x8 bw[2]; float ab[2];
#pragma unroll
    for (int nt2 = 0; nt2 < 2; ++nt2) {
      int n = nt2 * 16 + l15;
#pragma unroll
      for (int j = 0; j < 8; ++j)
        bw[nt2][j] = (__bf16)__float2bfloat16(attn_w[n * 32 + quad * 8 + j]);
      ab[nt2] = attn_b[n];
    }
    for (int mt = wave; mt < 7; mt += 4) {
      int row = mt * 16 + l15;
      int rc = row < 99 ? row : 99;
      bf16x8 af = *(const bf16x8*)(as_ + rc * 32 + quad * 8);
      f32x4 acc[2];
#pragma unroll
      for (int nt2 = 0; nt2 < 2; ++nt2)
        acc[nt2] = mfma16(af, bw[nt2], (f32x4){0.f, 0.f, 0.f, 0.f});
#pragma unroll
      for (int r = 0; r < 4; ++r) {
        int orow = mt * 16 + quad * 4 + r;
        if (orow < 100) {
          int ob = orow / 25, op = orow - ob * 25;
#pragma unroll
          for (int nt2 = 0; nt2 < 2; ++nt2)
            act[((size_t)(b0 + ob) * 25 + op) * 64 + 32 + nt2 * 16 + l15] =
                __float2bfloat16(fmaxf(acc[nt2][r] + ab[nt2], 0.f));
        }
      }
    }
  }
}

// ---------------- k2: fused dense chain (unchanged control; reads k1-produced w1bp/w2b) ----------------
__global__ __launch_bounds__(512) void k2(
    const __hip_bfloat16* __restrict__ act,
    const __hip_bfloat16* __restrict__ w1bp, const float* __restrict__ b1,
    const __hip_bfloat16* __restrict__ w2b, const float* __restrict__ b2,
    const float* __restrict__ w3, const float* __restrict__ b3,
    float* __restrict__ out) {
  const int t = threadIdx.x;
  const int lane = t & 63, wave = t >> 6;
  const int l15 = lane & 15, quad = lane >> 4;
  const int b0 = blockIdx.x * 16;

  __shared__ __hip_bfloat16 C1s[16 * 136];
  __shared__ __hip_bfloat16 C2s[16 * 72];

  f32x4 acc = {0.f, 0.f, 0.f, 0.f};
  const __bf16* ap = (const __bf16*)act + (size_t)(b0 + l15) * 1600 + quad * 8;
  const __bf16* bp = (const __bf16*)w1bp + (size_t)(wave * 16 + l15) * 1600 + quad * 8;
#pragma unroll 4
  for (int k0 = 0; k0 < 1600; k0 += 32) {
    bf16x8 av = *(const bf16x8*)(ap + k0);
    bf16x8 bv = *(const bf16x8*)(bp + k0);
    acc = mfma16(av, bv, acc);
  }
  {
    int col = wave * 16 + l15;
    float bias = b1[col];
#pragma unroll
    for (int r = 0; r < 4; ++r)
      C1s[(quad * 4 + r) * 136 + col] = __float2bfloat16(fmaxf(acc[r] + bias, 0.f));
  }
  __syncthreads();

  if (wave < 4) {
    f32x4 a2 = {0.f, 0.f, 0.f, 0.f};
    const __bf16* aL = (const __bf16*)C1s + l15 * 136 + quad * 8;
    const __bf16* bL = (const __bf16*)w2b + (wave * 16 + l15) * 128 + quad * 8;
#pragma unroll
    for (int k0 = 0; k0 < 128; k0 += 32)
      a2 = mfma16(*(const bf16x8*)(aL + k0), *(const bf16x8*)(bL + k0), a2);
    int col = wave * 16 + l15;
    float bias = b2[col];
#pragma unroll
    for (int r = 0; r < 4; ++r)
      C2s[(quad * 4 + r) * 72 + col] = __float2bfloat16(fmaxf(a2[r] + bias, 0.f));
  }
  __syncthreads();

  if (t < 80) {
    int row = t / 5, oc = t - row * 5;
    float s = b3[oc];
#pragma unroll
    for (int k = 0; k < 64; ++k)
      s += __bfloat162float(C2s[row * 72 + k]) * w3[oc * 64 + k];
    out[(size_t)(b0 + row) * 5 + oc] = s;
  }
}

extern "C" void kernel_launch(void* const* d_in, const int* in_sizes, int n_in,
                              void* d_out, int out_size, void* d_ws, size_t ws_size,
                              hipStream_t stream) {
  const float* x      = (const float*)d_in[0];
  const float* conv_w = (const float*)d_in[1];
  const float* conv_b = (const float*)d_in[2];
  const float* qkv_w  = (const float*)d_in[3];
  const float* qkv_b  = (const float*)d_in[4];
  const float* attn_w = (const float*)d_in[5];
  const float* attn_b = (const float*)d_in[6];
  const float* w1 = (const float*)d_in[7];
  const float* b1 = (const float*)d_in[8];
  const float* w2 = (const float*)d_in[9];
  const float* b2 = (const float*)d_in[10];
  const float* w3 = (const float*)d_in[11];
  const float* b3 = (const float*)d_in[12];
  float* out = (float*)d_out;

  // workspace layout (16B-aligned):
  //   act  [8192][25][64] bf16 : 26,214,400 B
  //   w1bp [128][1600]    bf16 :    409,600 B   (written by k1, read by k2)
  //   w2b  [64][128]      bf16 :     16,384 B
  char* ws = (char*)d_ws;
  __hip_bfloat16* act  = (__hip_bfloat16*)ws;
  __hip_bfloat16* w1bp = (__hip_bfloat16*)(ws + 26214400);
  __hip_bfloat16* w2b  = (__hip_bfloat16*)(ws + 26624000);

  k1<<<dim3(2048), dim3(256), 0, stream>>>(x, conv_w, conv_b, qkv_w, qkv_b,
                                           attn_w, attn_b, w1, w2, act, w1bp, w2b);
  k2<<<dim3(512), dim3(512), 0, stream>>>(act, w1bp, b1, w2b, b2, w3, b3, out);
}

// Round 6
// 206.625 us; speedup vs baseline: 1.0365x; 1.0365x over previous
//
#include <hip/hip_runtime.h>
#include <hip/hip_bf16.h>
#include <cstdint>
#include <cstddef>

// B=8192, CIN=16, 6x6->5x5 (k=2 VALID), FM=64, DK=DV=NH=32 (dkh=1), HID=128, OUT=5.
// R6 = R4-proven structure + R5's verified attention numerics + launch_bounds residency.
// act layout [b][pos][ch] (dense K-permuted); w1bp pre-permuted to match.

typedef __attribute__((ext_vector_type(4))) float f32x4;
typedef __attribute__((ext_vector_type(8))) __bf16 bf16x8;
typedef __attribute__((ext_vector_type(4))) __bf16 bf16x4;

#define LOG2E 1.4426950408889634f

// v_mfma_f32_16x16x32_bf16 (bench-verified layout R2-R5):
// A: lane holds A[m=lane&15][k=quad*8+j]; B: W[n=lane&15][k=quad*8+j];
// C/D: col=lane&15, row=quad*4+reg.
__device__ __forceinline__ f32x4 mfma16(bf16x8 a, bf16x8 b, f32x4 c) {
  return __builtin_amdgcn_mfma_f32_16x16x32_bf16(a, b, c, 0, 0, 0);
}

// ---------------- prep: weight casts / permutes (separate kernel — R4-proven) ----------------
__global__ __launch_bounds__(256) void prep(
    const float* __restrict__ conv_w, const float* __restrict__ qkv_w,
    const float* __restrict__ w1, const float* __restrict__ w2,
    __hip_bfloat16* __restrict__ wqb, __hip_bfloat16* __restrict__ w1bp,
    __hip_bfloat16* __restrict__ w2b) {
  int i = blockIdx.x * 256 + threadIdx.x;
  if (i < 128 * 1600) {
    int n = i / 1600, r = i - n * 1600;
    int c = r & 63, p = r >> 6;
    w1bp[i] = __float2bfloat16(w1[n * 1600 + c * 25 + p]);
  }
  if (i < 8192) {
    wqb[i] = __float2bfloat16(i < 2048 ? conv_w[i] : qkv_w[i - 2048]);
    w2b[i] = __float2bfloat16(w2[i]);
  }
}

// ---------------- k1: fused conv+qkv GEMM + attention + 1x1 conv ----------------
// 2048 blocks x 256 thr (4 waves); block = 4 batches -> GEMM M=100 (7 m-tiles).
// LDS: region A (6400 B) = xs (phase1: x bf16, 4*576) / as_ (phase2/3: [row][head], 100*32)
//      region B (27648 B) = qs [bl][ch 0..95][pos pad 36] (72 B rows; k ch pre-scaled log2e)
__global__ __launch_bounds__(256, 5) void k1(
    const float* __restrict__ x,
    const float* __restrict__ conv_b, const float* __restrict__ qkv_b,
    const __hip_bfloat16* __restrict__ wqb,
    const float* __restrict__ attn_w, const float* __restrict__ attn_b,
    __hip_bfloat16* __restrict__ act) {
  const int t = threadIdx.x;
  const int lane = t & 63, wave = t >> 6;
  const int l15 = lane & 15, quad = lane >> 4;
  const int b0 = blockIdx.x * 4;

  __shared__ __align__(16) char lds_raw[6400 + 27648];
  __bf16* xs  = (__bf16*)lds_raw;          // phase 1 (2304 elems)
  __bf16* as_ = (__bf16*)lds_raw;          // phase 2/3 (3200 elems, stride 32)
  __bf16* qs  = (__bf16*)(lds_raw + 6400); // q:0-31 k:32-63(x log2e) v:64-95, stride 36

  // ---- stage x -> bf16 LDS (2304 floats, coalesced) ----
  const float* xb = x + (size_t)b0 * 576;
#pragma unroll
  for (int i = 0; i < 9; ++i) {
    int f = t + i * 256;
    xs[f] = __float2bfloat16(xb[f]);
  }

  // ---- B-frags from bf16 wqb (R4-proven; 16 B/lane, hot small buffer) + biases ----
  bf16x8 bfr[8][2];
#pragma unroll
  for (int nt = 0; nt < 8; ++nt)
#pragma unroll
    for (int ks = 0; ks < 2; ++ks)
      bfr[nt][ks] = *(const bf16x8*)((const __bf16*)wqb + (nt * 16 + l15) * 64 + ks * 32 + quad * 8);
  float bias[8];
#pragma unroll
  for (int nt = 0; nt < 8; ++nt) {
    int ch = nt * 16 + l15;
    bias[nt] = (ch < 32) ? conv_b[ch] : qkv_b[ch - 32];
  }
  __syncthreads();

  // ---- phase 1: implicit GEMM, M=100, N=128, K=64 ----
  for (int mt = wave; mt < 7; mt += 4) {
    int row = mt * 16 + l15;
    int rc = row < 99 ? row : 99;
    int bl = rc / 25, pos = rc - bl * 25;
    int ii = pos / 5, jj = pos - ii * 5;
    const __bf16* xp = xs + bl * 576 + ii * 6 + jj;
    bf16x8 af[2];
#pragma unroll
    for (int ks = 0; ks < 2; ++ks) {
      const __bf16* p0 = xp + (ks * 8 + quad * 2) * 36;
      bf16x8 a;
      a[0] = p0[0];  a[1] = p0[1];  a[2] = p0[6];  a[3] = p0[7];
      a[4] = p0[36]; a[5] = p0[37]; a[6] = p0[42]; a[7] = p0[43];
      af[ks] = a;
    }
    f32x4 acc[8];
#pragma unroll
    for (int nt = 0; nt < 8; ++nt) acc[nt] = (f32x4){0.f, 0.f, 0.f, 0.f};
#pragma unroll
    for (int ks = 0; ks < 2; ++ks)
#pragma unroll
      for (int nt = 0; nt < 8; ++nt)
        acc[nt] = mfma16(af[ks], bfr[nt][ks], acc[nt]);

#pragma unroll
    for (int r = 0; r < 4; ++r) {
      int orow = mt * 16 + quad * 4 + r;
      if (orow < 100) {
        int ob = orow / 25, op = orow - ob * 25;
#pragma unroll
        for (int nt = 0; nt < 8; ++nt) {
          float v = acc[nt][r] + bias[nt];
          if (nt < 2) {  // conv_out ch 0..31 -> global with relu
            act[((size_t)(b0 + ob) * 25 + op) * 64 + nt * 16 + l15] =
                __float2bfloat16(fmaxf(v, 0.f));
          } else {       // qkv ch 0..95 -> LDS; k-channels (nt 4,5) pre-scaled by log2e
            if (nt == 4 || nt == 5) v *= LOG2E;
            qs[(ob * 96 + (nt - 2) * 16 + l15) * 36 + op] = __float2bfloat16(v);
          }
        }
      }
    }
  }
  __syncthreads();

  // ---- phase 2: attention, dkh=1; softmax without max-sub (|q.k| << fp32 exp range),
  //      e = exp2(q * k*log2e); 5 independent acc chains (R5-verified numerics).
  //      2 threads/head split i into 0..12 / 12..24 (i=12 dup, benign).
  {
    const int pair = t & 127, half = t >> 7;
    const int bl = pair >> 5, n = pair & 31;
    const __bf16* qp = qs + (bl * 96 + n) * 36;
    const __bf16* kp = qp + 32 * 36;
    const __bf16* vp = qp + 64 * 36;
    float kl[25], vv[25];
#pragma unroll
    for (int c4 = 0; c4 < 6; ++c4) {
      bf16x4 b = *(const bf16x4*)(kp + c4 * 4);
      bf16x4 c = *(const bf16x4*)(vp + c4 * 4);
#pragma unroll
      for (int z = 0; z < 4; ++z) {
        kl[c4 * 4 + z] = (float)b[z];
        vv[c4 * 4 + z] = (float)c[z];
      }
    }
    kl[24] = (float)kp[24]; vv[24] = (float)vp[24];

    const int i0 = half * 12;
    float qv[13];
    {
      const __bf16* qbase = qp + i0;  // byte off row*72 + i0*2: 8B-aligned for i0 in {0,12}
      bf16x4 q0 = *(const bf16x4*)(qbase);
      bf16x4 q1 = *(const bf16x4*)(qbase + 4);
      bf16x4 q2 = *(const bf16x4*)(qbase + 8);
#pragma unroll
      for (int z = 0; z < 4; ++z) {
        qv[z] = (float)q0[z]; qv[4 + z] = (float)q1[z]; qv[8 + z] = (float)q2[z];
      }
      qv[12] = (float)qbase[12];
    }

#pragma unroll
    for (int z = 0; z < 13; ++z) {
      const float qi = qv[z];
      float s0 = 0.f, s1 = 0.f, s2 = 0.f, s3 = 0.f, s4 = 0.f;
      float o0 = 0.f, o1 = 0.f, o2 = 0.f, o3 = 0.f, o4 = 0.f;
#pragma unroll
      for (int g = 0; g < 5; ++g) {
        float e0 = exp2f(qi * kl[g * 5 + 0]);
        float e1 = exp2f(qi * kl[g * 5 + 1]);
        float e2 = exp2f(qi * kl[g * 5 + 2]);
        float e3 = exp2f(qi * kl[g * 5 + 3]);
        float e4 = exp2f(qi * kl[g * 5 + 4]);
        s0 += e0; o0 = __builtin_fmaf(e0, vv[g * 5 + 0], o0);
        s1 += e1; o1 = __builtin_fmaf(e1, vv[g * 5 + 1], o1);
        s2 += e2; o2 = __builtin_fmaf(e2, vv[g * 5 + 2], o2);
        s3 += e3; o3 = __builtin_fmaf(e3, vv[g * 5 + 3], o3);
        s4 += e4; o4 = __builtin_fmaf(e4, vv[g * 5 + 4], o4);
      }
      float ss = ((s0 + s1) + (s2 + s3)) + s4;
      float oo = ((o0 + o1) + (o2 + o3)) + o4;
      as_[(bl * 25 + i0 + z) * 32 + n] = __float2bfloat16(oo * __builtin_amdgcn_rcpf(ss));
    }
  }
  __syncthreads();

  // ---- phase 3: 1x1 conv via MFMA. M=100 rows, K=32 heads, N=32 ----
  {
    bf16x8 bw[2]; float ab[2];
#pragma unroll
    for (int nt2 = 0; nt2 < 2; ++nt2) {
      int n = nt2 * 16 + l15;
#pragma unroll
      for (int j = 0; j < 8; ++j)
        bw[nt2][j] = (__bf16)__float2bfloat16(attn_w[n * 32 + quad * 8 + j]);
      ab[nt2] = attn_b[n];
    }
    for (int mt = wave; mt < 7; mt += 4) {
      int row = mt * 16 + l15;
      int rc = row < 99 ? row : 99;
      bf16x8 af = *(const bf16x8*)(as_ + rc * 32 + quad * 8);
      f32x4 acc[2];
#pragma unroll
      for (int nt2 = 0; nt2 < 2; ++nt2)
        acc[nt2] = mfma16(af, bw[nt2], (f32x4){0.f, 0.f, 0.f, 0.f});
#pragma unroll
      for (int r = 0; r < 4; ++r) {
        int orow = mt * 16 + quad * 4 + r;
        if (orow < 100) {
          int ob = orow / 25, op = orow - ob * 25;
#pragma unroll
          for (int nt2 = 0; nt2 < 2; ++nt2)
            act[((size_t)(b0 + ob) * 25 + op) * 64 + 32 + nt2 * 16 + l15] =
                __float2bfloat16(fmaxf(acc[nt2][r] + ab[nt2], 0.f));
        }
      }
    }
  }
}

// ---------------- k2: fused dense chain (unchanged control) ----------------
__global__ __launch_bounds__(512) void k2(
    const __hip_bfloat16* __restrict__ act,
    const __hip_bfloat16* __restrict__ w1bp, const float* __restrict__ b1,
    const __hip_bfloat16* __restrict__ w2b, const float* __restrict__ b2,
    const float* __restrict__ w3, const float* __restrict__ b3,
    float* __restrict__ out) {
  const int t = threadIdx.x;
  const int lane = t & 63, wave = t >> 6;
  const int l15 = lane & 15, quad = lane >> 4;
  const int b0 = blockIdx.x * 16;

  __shared__ __hip_bfloat16 C1s[16 * 136];
  __shared__ __hip_bfloat16 C2s[16 * 72];

  f32x4 acc = {0.f, 0.f, 0.f, 0.f};
  const __bf16* ap = (const __bf16*)act + (size_t)(b0 + l15) * 1600 + quad * 8;
  const __bf16* bp = (const __bf16*)w1bp + (size_t)(wave * 16 + l15) * 1600 + quad * 8;
#pragma unroll 4
  for (int k0 = 0; k0 < 1600; k0 += 32) {
    bf16x8 av = *(const bf16x8*)(ap + k0);
    bf16x8 bv = *(const bf16x8*)(bp + k0);
    acc = mfma16(av, bv, acc);
  }
  {
    int col = wave * 16 + l15;
    float bias = b1[col];
#pragma unroll
    for (int r = 0; r < 4; ++r)
      C1s[(quad * 4 + r) * 136 + col] = __float2bfloat16(fmaxf(acc[r] + bias, 0.f));
  }
  __syncthreads();

  if (wave < 4) {
    f32x4 a2 = {0.f, 0.f, 0.f, 0.f};
    const __bf16* aL = (const __bf16*)C1s + l15 * 136 + quad * 8;
    const __bf16* bL = (const __bf16*)w2b + (wave * 16 + l15) * 128 + quad * 8;
#pragma unroll
    for (int k0 = 0; k0 < 128; k0 += 32)
      a2 = mfma16(*(const bf16x8*)(aL + k0), *(const bf16x8*)(bL + k0), a2);
    int col = wave * 16 + l15;
    float bias = b2[col];
#pragma unroll
    for (int r = 0; r < 4; ++r)
      C2s[(quad * 4 + r) * 72 + col] = __float2bfloat16(fmaxf(a2[r] + bias, 0.f));
  }
  __syncthreads();

  if (t < 80) {
    int row = t / 5, oc = t - row * 5;
    float s = b3[oc];
#pragma unroll
    for (int k = 0; k < 64; ++k)
      s += __bfloat162float(C2s[row * 72 + k]) * w3[oc * 64 + k];
    out[(size_t)(b0 + row) * 5 + oc] = s;
  }
}

extern "C" void kernel_launch(void* const* d_in, const int* in_sizes, int n_in,
                              void* d_out, int out_size, void* d_ws, size_t ws_size,
                              hipStream_t stream) {
  const float* x      = (const float*)d_in[0];
  const float* conv_w = (const float*)d_in[1];
  const float* conv_b = (const float*)d_in[2];
  const float* qkv_w  = (const float*)d_in[3];
  const float* qkv_b  = (const float*)d_in[4];
  const float* attn_w = (const float*)d_in[5];
  const float* attn_b = (const float*)d_in[6];
  const float* w1 = (const float*)d_in[7];
  const float* b1 = (const float*)d_in[8];
  const float* w2 = (const float*)d_in[9];
  const float* b2 = (const float*)d_in[10];
  const float* w3 = (const float*)d_in[11];
  const float* b3 = (const float*)d_in[12];
  float* out = (float*)d_out;

  // workspace layout (16B-aligned):
  //   act  [8192][25][64] bf16 : 26,214,400 B
  //   w1bp [128][1600]    bf16 :    409,600 B
  //   w2b  [64][128]      bf16 :     16,384 B
  //   wqb  [128][64]      bf16 :     16,384 B
  char* ws = (char*)d_ws;
  __hip_bfloat16* act  = (__hip_bfloat16*)ws;
  __hip_bfloat16* w1bp = (__hip_bfloat16*)(ws + 26214400);
  __hip_bfloat16* w2b  = (__hip_bfloat16*)(ws + 26624000);
  __hip_bfloat16* wqb  = (__hip_bfloat16*)(ws + 26640384);

  prep<<<dim3(800), dim3(256), 0, stream>>>(conv_w, qkv_w, w1, w2, wqb, w1bp, w2b);
  k1<<<dim3(2048), dim3(256), 0, stream>>>(x, conv_b, qkv_b, wqb, attn_w, attn_b, act);
  k2<<<dim3(512), dim3(512), 0, stream>>>(act, w1bp, b1, w2b, b2, w3, b3, out);
}

// Round 7
// 177.272 us; speedup vs baseline: 1.2081x; 1.1656x over previous
//
#include <hip/hip_runtime.h>
#include <hip/hip_bf16.h>
#include <cstdint>
#include <cstddef>

// B=8192, CIN=16, 6x6->5x5 (k=2 VALID), FM=64, DK=DV=NH=32 (dkh=1), HID=128, OUT=5.
// R7 = R6 with raw-hw exp2 in attention + R2-proven 32-row k2.
// act layout [b][pos][ch] (dense K-permuted); w1bp pre-permuted to match.

typedef __attribute__((ext_vector_type(4))) float f32x4;
typedef __attribute__((ext_vector_type(8))) __bf16 bf16x8;
typedef __attribute__((ext_vector_type(4))) __bf16 bf16x4;

#define LOG2E 1.4426950408889634f

// raw v_exp_f32 (2^x). exp2f() lowers to the OCML wrapper (~4 extra VALU ops) —
// measured as the R4->R6 attention regression. Fallback is the R4-proven __expf path.
__device__ __forceinline__ float fast_exp2(float x) {
#if __has_builtin(__builtin_amdgcn_exp2f)
  return __builtin_amdgcn_exp2f(x);
#else
  return __expf(x * 0.6931471805599453f);
#endif
}

// v_mfma_f32_16x16x32_bf16 (bench-verified layout R2-R6):
// A: lane holds A[m=lane&15][k=quad*8+j]; B: W[n=lane&15][k=quad*8+j];
// C/D: col=lane&15, row=quad*4+reg.
__device__ __forceinline__ f32x4 mfma16(bf16x8 a, bf16x8 b, f32x4 c) {
  return __builtin_amdgcn_mfma_f32_16x16x32_bf16(a, b, c, 0, 0, 0);
}

// ---------------- prep: weight casts / permutes ----------------
__global__ __launch_bounds__(256) void prep(
    const float* __restrict__ conv_w, const float* __restrict__ qkv_w,
    const float* __restrict__ w1, const float* __restrict__ w2,
    __hip_bfloat16* __restrict__ wqb, __hip_bfloat16* __restrict__ w1bp,
    __hip_bfloat16* __restrict__ w2b) {
  int i = blockIdx.x * 256 + threadIdx.x;
  if (i < 128 * 1600) {
    int n = i / 1600, r = i - n * 1600;
    int c = r & 63, p = r >> 6;
    w1bp[i] = __float2bfloat16(w1[n * 1600 + c * 25 + p]);
  }
  if (i < 8192) {
    wqb[i] = __float2bfloat16(i < 2048 ? conv_w[i] : qkv_w[i - 2048]);
    w2b[i] = __float2bfloat16(w2[i]);
  }
}

// ---------------- k1: fused conv+qkv GEMM + attention + 1x1 conv ----------------
// 2048 blocks x 256 thr (4 waves); block = 4 batches -> GEMM M=100 (7 m-tiles).
__global__ __launch_bounds__(256) void k1(
    const float* __restrict__ x,
    const float* __restrict__ conv_b, const float* __restrict__ qkv_b,
    const __hip_bfloat16* __restrict__ wqb,
    const float* __restrict__ attn_w, const float* __restrict__ attn_b,
    __hip_bfloat16* __restrict__ act) {
  const int t = threadIdx.x;
  const int lane = t & 63, wave = t >> 6;
  const int l15 = lane & 15, quad = lane >> 4;
  const int b0 = blockIdx.x * 4;

  __shared__ __align__(16) char lds_raw[6400 + 27648];
  __bf16* xs  = (__bf16*)lds_raw;          // phase 1 (2304 elems)
  __bf16* as_ = (__bf16*)lds_raw;          // phase 2/3 (3200 elems, stride 32)
  __bf16* qs  = (__bf16*)(lds_raw + 6400); // q:0-31 k:32-63(x log2e) v:64-95, stride 36

  // ---- stage x -> bf16 LDS ----
  const float* xb = x + (size_t)b0 * 576;
#pragma unroll
  for (int i = 0; i < 9; ++i) {
    int f = t + i * 256;
    xs[f] = __float2bfloat16(xb[f]);
  }

  // ---- B-frags from bf16 wqb + biases ----
  bf16x8 bfr[8][2];
#pragma unroll
  for (int nt = 0; nt < 8; ++nt)
#pragma unroll
    for (int ks = 0; ks < 2; ++ks)
      bfr[nt][ks] = *(const bf16x8*)((const __bf16*)wqb + (nt * 16 + l15) * 64 + ks * 32 + quad * 8);
  float bias[8];
#pragma unroll
  for (int nt = 0; nt < 8; ++nt) {
    int ch = nt * 16 + l15;
    bias[nt] = (ch < 32) ? conv_b[ch] : qkv_b[ch - 32];
  }
  __syncthreads();

  // ---- phase 1: implicit GEMM, M=100, N=128, K=64 ----
  for (int mt = wave; mt < 7; mt += 4) {
    int row = mt * 16 + l15;
    int rc = row < 99 ? row : 99;
    int bl = rc / 25, pos = rc - bl * 25;
    int ii = pos / 5, jj = pos - ii * 5;
    const __bf16* xp = xs + bl * 576 + ii * 6 + jj;
    bf16x8 af[2];
#pragma unroll
    for (int ks = 0; ks < 2; ++ks) {
      const __bf16* p0 = xp + (ks * 8 + quad * 2) * 36;
      bf16x8 a;
      a[0] = p0[0];  a[1] = p0[1];  a[2] = p0[6];  a[3] = p0[7];
      a[4] = p0[36]; a[5] = p0[37]; a[6] = p0[42]; a[7] = p0[43];
      af[ks] = a;
    }
    f32x4 acc[8];
#pragma unroll
    for (int nt = 0; nt < 8; ++nt) acc[nt] = (f32x4){0.f, 0.f, 0.f, 0.f};
#pragma unroll
    for (int ks = 0; ks < 2; ++ks)
#pragma unroll
      for (int nt = 0; nt < 8; ++nt)
        acc[nt] = mfma16(af[ks], bfr[nt][ks], acc[nt]);

#pragma unroll
    for (int r = 0; r < 4; ++r) {
      int orow = mt * 16 + quad * 4 + r;
      if (orow < 100) {
        int ob = orow / 25, op = orow - ob * 25;
#pragma unroll
        for (int nt = 0; nt < 8; ++nt) {
          float v = acc[nt][r] + bias[nt];
          if (nt < 2) {  // conv_out ch 0..31 -> global with relu
            act[((size_t)(b0 + ob) * 25 + op) * 64 + nt * 16 + l15] =
                __float2bfloat16(fmaxf(v, 0.f));
          } else {       // qkv ch 0..95 -> LDS; k-channels (nt 4,5) pre-scaled by log2e
            if (nt == 4 || nt == 5) v *= LOG2E;
            qs[(ob * 96 + (nt - 2) * 16 + l15) * 36 + op] = __float2bfloat16(v);
          }
        }
      }
    }
  }
  __syncthreads();

  // ---- phase 2: attention, dkh=1; softmax without max-sub (|q.k| << fp32 exp range),
  //      e = 2^(q * k*log2e) via raw v_exp_f32; 5 independent acc chains.
  {
    const int pair = t & 127, half = t >> 7;
    const int bl = pair >> 5, n = pair & 31;
    const __bf16* qp = qs + (bl * 96 + n) * 36;
    const __bf16* kp = qp + 32 * 36;
    const __bf16* vp = qp + 64 * 36;
    float kl[25], vv[25];
#pragma unroll
    for (int c4 = 0; c4 < 6; ++c4) {
      bf16x4 b = *(const bf16x4*)(kp + c4 * 4);
      bf16x4 c = *(const bf16x4*)(vp + c4 * 4);
#pragma unroll
      for (int z = 0; z < 4; ++z) {
        kl[c4 * 4 + z] = (float)b[z];
        vv[c4 * 4 + z] = (float)c[z];
      }
    }
    kl[24] = (float)kp[24]; vv[24] = (float)vp[24];

    const int i0 = half * 12;
    float qv[13];
    {
      const __bf16* qbase = qp + i0;
      bf16x4 q0 = *(const bf16x4*)(qbase);
      bf16x4 q1 = *(const bf16x4*)(qbase + 4);
      bf16x4 q2 = *(const bf16x4*)(qbase + 8);
#pragma unroll
      for (int z = 0; z < 4; ++z) {
        qv[z] = (float)q0[z]; qv[4 + z] = (float)q1[z]; qv[8 + z] = (float)q2[z];
      }
      qv[12] = (float)qbase[12];
    }

#pragma unroll
    for (int z = 0; z < 13; ++z) {
      const float qi = qv[z];
      float s0 = 0.f, s1 = 0.f, s2 = 0.f, s3 = 0.f, s4 = 0.f;
      float o0 = 0.f, o1 = 0.f, o2 = 0.f, o3 = 0.f, o4 = 0.f;
#pragma unroll
      for (int g = 0; g < 5; ++g) {
        float e0 = fast_exp2(qi * kl[g * 5 + 0]);
        float e1 = fast_exp2(qi * kl[g * 5 + 1]);
        float e2 = fast_exp2(qi * kl[g * 5 + 2]);
        float e3 = fast_exp2(qi * kl[g * 5 + 3]);
        float e4 = fast_exp2(qi * kl[g * 5 + 4]);
        s0 += e0; o0 = __builtin_fmaf(e0, vv[g * 5 + 0], o0);
        s1 += e1; o1 = __builtin_fmaf(e1, vv[g * 5 + 1], o1);
        s2 += e2; o2 = __builtin_fmaf(e2, vv[g * 5 + 2], o2);
        s3 += e3; o3 = __builtin_fmaf(e3, vv[g * 5 + 3], o3);
        s4 += e4; o4 = __builtin_fmaf(e4, vv[g * 5 + 4], o4);
      }
      float ss = ((s0 + s1) + (s2 + s3)) + s4;
      float oo = ((o0 + o1) + (o2 + o3)) + o4;
      as_[(bl * 25 + i0 + z) * 32 + n] = __float2bfloat16(oo * __builtin_amdgcn_rcpf(ss));
    }
  }
  __syncthreads();

  // ---- phase 3: 1x1 conv via MFMA. M=100 rows, K=32 heads, N=32 ----
  {
    bf16x8 bw[2]; float ab[2];
#pragma unroll
    for (int nt2 = 0; nt2 < 2; ++nt2) {
      int n = nt2 * 16 + l15;
#pragma unroll
      for (int j = 0; j < 8; ++j)
        bw[nt2][j] = (__bf16)__float2bfloat16(attn_w[n * 32 + quad * 8 + j]);
      ab[nt2] = attn_b[n];
    }
    for (int mt = wave; mt < 7; mt += 4) {
      int row = mt * 16 + l15;
      int rc = row < 99 ? row : 99;
      bf16x8 af = *(const bf16x8*)(as_ + rc * 32 + quad * 8);
      f32x4 acc[2];
#pragma unroll
      for (int nt2 = 0; nt2 < 2; ++nt2)
        acc[nt2] = mfma16(af, bw[nt2], (f32x4){0.f, 0.f, 0.f, 0.f});
#pragma unroll
      for (int r = 0; r < 4; ++r) {
        int orow = mt * 16 + quad * 4 + r;
        if (orow < 100) {
          int ob = orow / 25, op = orow - ob * 25;
#pragma unroll
          for (int nt2 = 0; nt2 < 2; ++nt2)
            act[((size_t)(b0 + ob) * 25 + op) * 64 + 32 + nt2 * 16 + l15] =
                __float2bfloat16(fmaxf(acc[nt2][r] + ab[nt2], 0.f));
        }
      }
    }
  }
}

// ---------------- k2: fused dense chain — R2-proven 32-row/2-acc shape ----------------
// 256 blocks x 512 thr (8 waves = 2 wm x 4 wn); block = 32 rows.
__global__ __launch_bounds__(512) void k2(
    const __hip_bfloat16* __restrict__ act,
    const __hip_bfloat16* __restrict__ w1bp, const float* __restrict__ b1,
    const __hip_bfloat16* __restrict__ w2b, const float* __restrict__ b2,
    const float* __restrict__ w3, const float* __restrict__ b3,
    float* __restrict__ out) {
  const int t = threadIdx.x;
  const int lane = t & 63;
  const int wave = t >> 6;   // 0..7
  const int wm = wave >> 2;  // 0..1
  const int wn = wave & 3;   // 0..3
  const int l15 = lane & 15;
  const int quad = lane >> 4;  // 0..3
  const int b0 = blockIdx.x * 32;

  __shared__ __hip_bfloat16 C1s[32 * 136];
  __shared__ __hip_bfloat16 C2s[32 * 72];

  // ---- layer 1: [32,1600] x [128,1600]^T ----
  f32x4 acc0 = {0.f, 0.f, 0.f, 0.f};
  f32x4 acc1 = {0.f, 0.f, 0.f, 0.f};
  const __bf16* aptr  = (const __bf16*)act + (size_t)(b0 + wm * 16 + l15) * 1600 + quad * 8;
  const __bf16* bptr0 = (const __bf16*)w1bp + (size_t)(wn * 32 + l15) * 1600 + quad * 8;
  const __bf16* bptr1 = bptr0 + 16 * 1600;
#pragma unroll 5
  for (int k0 = 0; k0 < 1600; k0 += 32) {
    bf16x8 av  = *(const bf16x8*)(aptr + k0);
    bf16x8 bv0 = *(const bf16x8*)(bptr0 + k0);
    bf16x8 bv1 = *(const bf16x8*)(bptr1 + k0);
    acc0 = mfma16(av, bv0, acc0);
    acc1 = mfma16(av, bv1, acc1);
  }
  {
    const int col0 = wn * 32 + l15;
    const float bias0 = b1[col0];
    const float bias1 = b1[col0 + 16];
#pragma unroll
    for (int r = 0; r < 4; ++r) {
      const int row = wm * 16 + quad * 4 + r;
      C1s[row * 136 + col0]      = __float2bfloat16(fmaxf(acc0[r] + bias0, 0.f));
      C1s[row * 136 + col0 + 16] = __float2bfloat16(fmaxf(acc1[r] + bias1, 0.f));
    }
  }
  __syncthreads();

  // ---- layer 2: [32,128] x [64,128]^T ----
  f32x4 acc2 = {0.f, 0.f, 0.f, 0.f};
  {
    const __bf16* aL = (const __bf16*)C1s + (wm * 16 + l15) * 136 + quad * 8;
    const __bf16* bL = (const __bf16*)w2b + (wn * 16 + l15) * 128 + quad * 8;
#pragma unroll
    for (int k0 = 0; k0 < 128; k0 += 32)
      acc2 = mfma16(*(const bf16x8*)(aL + k0), *(const bf16x8*)(bL + k0), acc2);
  }
  {
    const int col = wn * 16 + l15;
    const float bias = b2[col];
#pragma unroll
    for (int r = 0; r < 4; ++r) {
      const int row = wm * 16 + quad * 4 + r;
      C2s[row * 72 + col] = __float2bfloat16(fmaxf(acc2[r] + bias, 0.f));
    }
  }
  __syncthreads();

  // ---- layer 3 (scalar, 160 outputs) ----
  if (t < 160) {
    const int row = t / 5;
    const int oc = t - row * 5;
    float s = b3[oc];
#pragma unroll
    for (int k = 0; k < 64; ++k)
      s += __bfloat162float(C2s[row * 72 + k]) * w3[oc * 64 + k];
    out[(size_t)(b0 + row) * 5 + oc] = s;
  }
}

extern "C" void kernel_launch(void* const* d_in, const int* in_sizes, int n_in,
                              void* d_out, int out_size, void* d_ws, size_t ws_size,
                              hipStream_t stream) {
  const float* x      = (const float*)d_in[0];
  const float* conv_w = (const float*)d_in[1];
  const float* conv_b = (const float*)d_in[2];
  const float* qkv_w  = (const float*)d_in[3];
  const float* qkv_b  = (const float*)d_in[4];
  const float* attn_w = (const float*)d_in[5];
  const float* attn_b = (const float*)d_in[6];
  const float* w1 = (const float*)d_in[7];
  const float* b1 = (const float*)d_in[8];
  const float* w2 = (const float*)d_in[9];
  const float* b2 = (const float*)d_in[10];
  const float* w3 = (const float*)d_in[11];
  const float* b3 = (const float*)d_in[12];
  float* out = (float*)d_out;

  // workspace layout (16B-aligned):
  //   act  [8192][25][64] bf16 : 26,214,400 B
  //   w1bp [128][1600]    bf16 :    409,600 B
  //   w2b  [64][128]      bf16 :     16,384 B
  //   wqb  [128][64]      bf16 :     16,384 B
  char* ws = (char*)d_ws;
  __hip_bfloat16* act  = (__hip_bfloat16*)ws;
  __hip_bfloat16* w1bp = (__hip_bfloat16*)(ws + 26214400);
  __hip_bfloat16* w2b  = (__hip_bfloat16*)(ws + 26624000);
  __hip_bfloat16* wqb  = (__hip_bfloat16*)(ws + 26640384);

  prep<<<dim3(800), dim3(256), 0, stream>>>(conv_w, qkv_w, w1, w2, wqb, w1bp, w2b);
  k1<<<dim3(2048), dim3(256), 0, stream>>>(x, conv_b, qkv_b, wqb, attn_w, attn_b, act);
  k2<<<dim3(256), dim3(512), 0, stream>>>(act, w1bp, b1, w2b, b2, w3, b3, out);
}